// Round 1
// baseline (100.236 us; speedup 1.0000x reference)
//
#include <hip/hip_runtime.h>

// Box_diamond: soft-product gate network.
// out[b,p] = softprod_m(1 - y1[b,p,m]*W2[p,m]),
// y1[b,p,m] = softprod_l(1 - x[b, (p/4)*32 + l*4 + (p%4)] * sigmoid(d*(t2[p]-d))), d=l-m
// softprod(X) = -1/(-1 + sum log X) = 1/(1 - ln(prod X)).
// Key facts: W1,W2 <= 0.5 => every product factor >= 0.5 => prod of 8 >= 2^-8,
// so we can take ONE log of the product instead of summing 8 logs.

constexpr int BDIM   = 4096;
constexpr int IN_DIM = 4096;
constexpr int PDIM   = 512;
constexpr int PT = 64;   // p per block
constexpr int BT = 32;   // b per block
constexpr float LN2 = 0.69314718055994530942f;

__global__ __launch_bounds__(256, 4)
void box_kernel(const float* __restrict__ x,
                const float* __restrict__ t0,
                const float* __restrict__ t1,
                const float* __restrict__ t2,
                float* __restrict__ out)
{
    // padded strides 17/9 (odd) -> 2-way LDS bank aliasing only (free)
    __shared__ float w1s[PT][17];
    __shared__ float w2s[PT][9];

    const int p0 = blockIdx.x * PT;
    const int b0 = blockIdx.y * BT;
    const int t  = threadIdx.x;

    // Build per-p gate tables (threads 0..63, one p each).
    if (t < PT) {
        const int p = p0 + t;
        const float t0p = t0[p], t1p = t1[p], t2p = t2[p];
#pragma unroll
        for (int d = -7; d <= 7; ++d) {
            const float fd = (float)d;
            const float z  = fd * (t2p - fd);           // <= 0 always
            w1s[t][d + 7] = 1.0f / (1.0f + __expf(-z));
        }
#pragma unroll
        for (int m = 0; m < 8; ++m) {
            const float fm = (float)m;
            const float za = (fm - t0p) * (t1p - fm);
            const float zb = (7.0f - t2p - fm) * fm;
            w2s[t][m] = (1.0f / (1.0f + __expf(-za))) * (1.0f / (1.0f + __expf(-zb)));
        }
    }
    __syncthreads();

    const int pl = t & 63;           // p_local: one p per thread
    const int p  = p0 + pl;
    const int g  = p >> 2;
    const int j  = p & 3;

    // tables to registers (23 VGPRs)
    float w1d[15];
#pragma unroll
    for (int i = 0; i < 15; ++i) w1d[i] = w1s[pl][i];
    float w2[8];
#pragma unroll
    for (int m = 0; m < 8; ++m) w2[m] = w2s[pl][m];

    const int bstart = b0 + (t >> 6);                 // wave id -> b offset 0..3
    const float* xbase = x + (size_t)bstart * IN_DIM + g * 32 + j;
    float*       obase = out + (size_t)bstart * PDIM + p;

    for (int bi = 0; bi < BT / 4; ++bi) {
        const float* xp = xbase + (size_t)(bi * 4) * IN_DIM;
        float xv[8];
#pragma unroll
        for (int l = 0; l < 8; ++l) xv[l] = xp[l * 4];

        float prod2 = 1.0f;
#pragma unroll
        for (int m = 0; m < 8; ++m) {
            float prod1 = 1.0f;
#pragma unroll
            for (int l = 0; l < 8; ++l)
                prod1 *= (1.0f - xv[l] * w1d[l - m + 7]);
            // y1 = 1/(1 - ln(prod1)); denom >= 1
            const float y1 = __builtin_amdgcn_rcpf(1.0f - LN2 * __log2f(prod1));
            prod2 *= (1.0f - y1 * w2[m]);
        }
        obase[(size_t)(bi * 4) * PDIM] =
            __builtin_amdgcn_rcpf(1.0f - LN2 * __log2f(prod2));
    }
}

extern "C" void kernel_launch(void* const* d_in, const int* in_sizes, int n_in,
                              void* d_out, int out_size, void* d_ws, size_t ws_size,
                              hipStream_t stream)
{
    const float* x  = (const float*)d_in[0];
    const float* t0 = (const float*)d_in[1];
    const float* t1 = (const float*)d_in[2];
    const float* t2 = (const float*)d_in[3];
    float* out = (float*)d_out;

    dim3 grid(PDIM / PT, BDIM / BT);   // (8, 128) = 1024 blocks
    box_kernel<<<grid, 256, 0, stream>>>(x, t0, t1, t2, out);
}